// Round 6
// baseline (291.967 us; speedup 1.0000x reference)
//
#include <hip/hip_runtime.h>
#include <cstdint>

typedef __attribute__((ext_vector_type(8))) short bf16x8;   // 8 bf16 = 4 VGPRs
typedef __attribute__((ext_vector_type(4))) float f32x4;    // MFMA C/D
typedef __attribute__((ext_vector_type(4))) float f4;
typedef __attribute__((ext_vector_type(4))) unsigned short u16x4;
typedef __attribute__((ext_vector_type(8))) unsigned short u16x8;
typedef unsigned short u16;

__device__ __forceinline__ u16 f2bf(float f) {
  uint32_t u = __builtin_bit_cast(uint32_t, f);
  u += 0x7fffu + ((u >> 16) & 1u);          // round-to-nearest-even
  return (u16)(u >> 16);
}

__device__ __forceinline__ void async_cp16(const void* g, void* l) {
  __builtin_amdgcn_global_load_lds(
      (const __attribute__((address_space(1))) uint32_t*)g,
      (__attribute__((address_space(3))) uint32_t*)l, 16, 0, 0);
}

// cast x | features | prototypes -> contiguous bf16 region in ws.
// Also zeroes gemm3's per-tile arrival counters (ws is 0xAA-poisoned per call).
__global__ __launch_bounds__(256) void cast3(
    const float* __restrict__ x, const float* __restrict__ f,
    const float* __restrict__ p, u16* __restrict__ dst,
    int* __restrict__ cnt, int n1, int n2, int n3) {
  if (blockIdx.x == 0) cnt[threadIdx.x] = 0;   // 256 tile counters
  int i = (blockIdx.x * 256 + threadIdx.x) * 4;
  const float* src;
  int local;
  if (i < n1) { src = x; local = i; }
  else if (i < n1 + n2) { src = f; local = i - n1; }
  else if (i < n1 + n2 + n3) { src = p; local = i - n1 - n2; }
  else return;
  f4 v = *(const f4*)(src + local);
  u16x4 o;
  o.x = f2bf(v.x); o.y = f2bf(v.y); o.z = f2bf(v.z); o.w = f2bf(v.w);
  *(u16x4*)(dst + i) = o;
}

// ---- shared main loop: C += A(tile, MxK-rowmajor) @ B(tile, NxK-rowmajor)^T ----
// A,B pre-offset to the tile base row. 16B-chunk XOR swizzle (verified 0 bank conflicts).
template<int TM, int TN>
__device__ __forceinline__ void mainloop(
    const u16* __restrict__ A, const u16* __restrict__ B, int K,
    int kbeg, int kend, int tid, u16* lds, f32x4 (&acc)[TM / 32][TN / 32]) {
  constexpr int BK = 64;
  constexpr int WM = TM / 2, WN = TN / 2;
  constexpr int MT = TM / 32, NT = TN / 32;
  const int lane = tid & 63;
  const int wave = tid >> 6;
  const int wrow = wave >> 1, wcol = wave & 1;

  for (int k0 = kbeg; k0 < kend; k0 += BK) {
    #pragma unroll
    for (int it = 0; it < TM / 32; ++it) {
      int c = it * 256 + tid;            // chunk index = LDS position
      int row = c >> 3, pc = c & 7;
      int gc = pc ^ (row & 7);           // which global 16B chunk lands here
      async_cp16(A + (size_t)row * K + (k0 + gc * 8),
                 &lds[(it * 256 + wave * 64) * 8]);
    }
    #pragma unroll
    for (int it = 0; it < TN / 32; ++it) {
      int c = it * 256 + tid;
      int row = c >> 3, pc = c & 7;
      int gc = pc ^ (row & 7);
      async_cp16(B + (size_t)row * K + (k0 + gc * 8),
                 &lds[TM * BK + (it * 256 + wave * 64) * 8]);
    }
    __syncthreads();

    #pragma unroll
    for (int s = 0; s < 2; ++s) {
      const int h = s * 4 + (lane >> 4);
      bf16x8 afr[MT], bfr[NT];
      #pragma unroll
      for (int i = 0; i < MT; ++i) {
        int r = wrow * WM + i * 16 + (lane & 15);
        afr[i] = *(const bf16x8*)&lds[(r * 8 + (h ^ (r & 7))) * 8];
      }
      #pragma unroll
      for (int j = 0; j < NT; ++j) {
        int r = wcol * WN + j * 16 + (lane & 15);
        bfr[j] = *(const bf16x8*)&lds[TM * BK + (r * 8 + (h ^ (r & 7))) * 8];
      }
      #pragma unroll
      for (int i = 0; i < MT; ++i)
        #pragma unroll
        for (int j = 0; j < NT; ++j)
          acc[i][j] = __builtin_amdgcn_mfma_f32_16x16x32_bf16(afr[i], bfr[j], acc[i][j], 0, 0, 0);
    }
    __syncthreads();
  }
}

// ---- GEMM1+GEMM2 merged: [x; proto](4608 x 1024) @ feat^T, tile 128x64 ----
// x-rows  -> Acat[row, f]=xf*relu(xf), Acat[row, 2048+f]=1-relu(xf)
// p-rows  -> Bcat[row, f]=th*c-al*(1-pres), Bcat[row, 2048+f]=-be*c
// Epilogue: LDS transpose (stride 72 u16, 16B-aligned rows) -> 128B-coalesced
// u16x8 global stores. launch_bounds(256,5): 5 blocks/CU (VGPR cap 102).
__global__ __launch_bounds__(256, 5) void gemm12(
    const u16* __restrict__ xb, const u16* __restrict__ pb,
    const u16* __restrict__ fb, u16* __restrict__ Acat, u16* __restrict__ Bcat,
    const float* __restrict__ alpha, const float* __restrict__ beta,
    const float* __restrict__ theta) {
  constexpr int TM = 128, TN = 64, K = 1024, N = 2048;
  constexpr int MT = TM / 32, NT = TN / 32;    // 4, 2
  constexpr int TSTRIDE = 72;            // u16; 144B rows = 9*16B aligned
  __shared__ u16 lds[(TM + TN) * 64];    // 24576 B; transpose uses 128*72*2=18432 B

  const int tid = threadIdx.x;
  const int lane = tid & 63;
  const int wave = tid >> 6;
  const int wrow = wave >> 1, wcol = wave & 1;
  const int bm_all = blockIdx.x * TM;
  const int bn = blockIdx.y * TN;
  const bool is_x = bm_all < 4096;       // 4096 % 128 == 0: block purely x or proto
  const u16* A = is_x ? xb + (size_t)bm_all * K : pb + (size_t)(bm_all - 4096) * K;
  const u16* B = fb + (size_t)bn * K;

  f32x4 acc[MT][NT] = {};
  mainloop<TM, TN>(A, B, K, 0, K, tid, lds, acc);

  float th = 0.f, al = 0.f, be = 0.f;
  if (!is_x) { th = theta[0]; al = alpha[0]; be = beta[0]; }
  u16* dst = is_x ? Acat : Bcat;
  const int rowbase = is_x ? bm_all : bm_all - 4096;

  #pragma unroll
  for (int half = 0; half < 2; ++half) {
    __syncthreads();   // protect lds reuse (mainloop end / previous half's reads)
    #pragma unroll
    for (int i = 0; i < MT; ++i) {
      #pragma unroll
      for (int j = 0; j < NT; ++j) {
        const int cl = wcol * 32 + j * 16 + (lane & 15);
        #pragma unroll
        for (int r = 0; r < 4; ++r) {
          const int rl = wrow * 64 + i * 16 + (lane >> 4) * 4 + r;
          float v = acc[i][j][r];
          float pres = v > 0.f ? v : 0.f;
          float o;
          if (is_x) o = half == 0 ? v * pres : 1.f - pres;
          else {
            float cc = v * pres;
            o = half == 0 ? th * cc - al * (1.f - pres) : -be * cc;
          }
          lds[rl * TSTRIDE + cl] = f2bf(o);
        }
      }
    }
    __syncthreads();
    #pragma unroll
    for (int v = 0; v < 4; ++v) {
      const int rl = v * 32 + (tid >> 3);
      const int cl = (tid & 7) * 8;
      u16x8 vec = *(const u16x8*)&lds[rl * TSTRIDE + cl];
      *(u16x8*)&dst[(size_t)(rowbase + rl) * (2 * N) + bn + cl + half * N] = vec;
    }
  }
}

// ---- GEMM3 split-K + fused reduce: out = Acat @ Bcat^T over K=4096 ----
// Each z-block stores its partial (thread-linear, coalesced); the LAST arriver
// per tile (device-scope atomic counter) sums the 4 partials and writes out.
// Deterministic (fixed z-order sum). launch_bounds(256,6): 6 blocks/CU.
__global__ __launch_bounds__(256, 6) void gemm3(
    const u16* __restrict__ Acat, const u16* __restrict__ Bcat,
    float* __restrict__ part, int* __restrict__ cnt, float* __restrict__ out) {
  constexpr int TM = 128, TN = 64, K = 4096, N = 512, KSPLIT = 4;
  constexpr int MT = TM / 32, NT = TN / 32;    // 4, 2
  __shared__ u16 lds[(TM + TN) * 64];    // 24576 B

  const int tid = threadIdx.x;
  const int lane = tid & 63;
  const int wave = tid >> 6;
  const int wrow = wave >> 1, wcol = wave & 1;
  const int bm = blockIdx.x * TM;
  const int bn = blockIdx.y * TN;
  const int kbeg = blockIdx.z * (K / KSPLIT);
  const int kend = kbeg + (K / KSPLIT);
  const int tileId = blockIdx.y * 32 + blockIdx.x;   // 0..255

  f32x4 acc[MT][NT] = {};
  mainloop<TM, TN>(Acat + (size_t)bm * K, Bcat + (size_t)bn * K, K, kbeg, kend,
                   tid, lds, acc);

  // store own partial, thread-linear (perfectly coalesced f32x4)
  #pragma unroll
  for (int i = 0; i < MT; ++i)
    #pragma unroll
    for (int j = 0; j < NT; ++j)
      *(f4*)&part[((size_t)blockIdx.z * 256 + tileId) * 8192 +
                  (i * NT + j) * 1024 + tid * 4] = acc[i][j];

  __threadfence();                       // release partial stores device-scope
  __syncthreads();                       // all threads' stores fenced
  volatile int* flag = (volatile int*)lds;
  if (tid == 0) {
    int prev = atomicAdd(&cnt[tileId], 1);   // device-scope by default
    *flag = (prev == KSPLIT - 1) ? 1 : 0;
  }
  __syncthreads();
  if (*flag) {
    __threadfence();                     // acquire: see other blocks' partials
    #pragma unroll
    for (int s = 0; s < 8; ++s) {
      f4 v = {0.f, 0.f, 0.f, 0.f};
      #pragma unroll
      for (int z = 0; z < 4; ++z)
        v += *(const f4*)&part[((size_t)z * 256 + tileId) * 8192 + s * 1024 + tid * 4];
      const int i = s >> 1, j = s & 1;
      const int gr0 = bm + wrow * 64 + i * 16 + (lane >> 4) * 4;
      const int gc = bn + wcol * 32 + j * 16 + (lane & 15);
      out[(size_t)(gr0 + 0) * N + gc] = v.x;
      out[(size_t)(gr0 + 1) * N + gc] = v.y;
      out[(size_t)(gr0 + 2) * N + gc] = v.z;
      out[(size_t)(gr0 + 3) * N + gc] = v.w;
    }
  }
}

extern "C" void kernel_launch(void* const* d_in, const int* in_sizes, int n_in,
                              void* d_out, int out_size, void* d_ws, size_t ws_size,
                              hipStream_t stream) {
  const float* x     = (const float*)d_in[0];
  const float* feat  = (const float*)d_in[1];
  const float* proto = (const float*)d_in[2];
  const float* alpha = (const float*)d_in[3];
  const float* beta  = (const float*)d_in[4];
  const float* theta = (const float*)d_in[5];
  float* out = (float*)d_out;

  constexpr int Bb = 4096, Ii = 1024, Pp = 512, Ff = 2048;

  // ws layout: region0 [0, 33.5MB) serves cast outputs (consumed by gemm12),
  // then is reused for gemm3's fp32 partials (written after gemm12 is done).
  char* ws = (char*)d_ws;
  u16* xb    = (u16*)ws;                              // 8.4 MB
  u16* fb    = xb + (size_t)Bb * Ii;                  // 4.2 MB
  u16* pb    = fb + (size_t)Ff * Ii;                  // 1.0 MB
  float* part = (float*)ws;                           // 33.5 MB (aliases casts)
  size_t r0 = (size_t)4 * 256 * 8192 * 4;             // 33.55 MB
  u16* Acat = (u16*)(ws + r0);                        // 33.6 MB
  u16* Bcat = Acat + (size_t)Bb * 2 * Ff;             // 4.2 MB
  int* cnt  = (int*)(Bcat + (size_t)Pp * 2 * Ff);     // 1 KB (256 counters)

  const int n1 = Bb * Ii, n2 = Ff * Ii, n3 = Pp * Ii;
  cast3<<<((n1 + n2 + n3) / 4 + 255) / 256, 256, 0, stream>>>(
      x, feat, proto, xb, cnt, n1, n2, n3);

  // merged GEMM1+GEMM2: M=4608 (36 row-tiles of 128), N=2048 (32 col-tiles of 64)
  gemm12<<<dim3(36, 32), 256, 0, stream>>>(xb, pb, fb, Acat, Bcat, alpha, beta, theta);

  // GEMM3: 4096x512, K=4096 split 4 ways -> 1024 blocks; last arriver reduces
  gemm3<<<dim3(Bb / 128, Pp / 64, 4), 256, 0, stream>>>(Acat, Bcat, part, cnt, out);
}

// Round 7
// 286.340 us; speedup vs baseline: 1.0197x; 1.0197x over previous
//
#include <hip/hip_runtime.h>
#include <cstdint>

typedef __attribute__((ext_vector_type(8))) short bf16x8;   // 8 bf16 = 4 VGPRs
typedef __attribute__((ext_vector_type(4))) float f32x4;    // MFMA C/D
typedef __attribute__((ext_vector_type(4))) float f4;
typedef __attribute__((ext_vector_type(4))) unsigned short u16x4;
typedef __attribute__((ext_vector_type(8))) unsigned short u16x8;
typedef unsigned short u16;

__device__ __forceinline__ u16 f2bf(float f) {
  uint32_t u = __builtin_bit_cast(uint32_t, f);
  u += 0x7fffu + ((u >> 16) & 1u);          // round-to-nearest-even
  return (u16)(u >> 16);
}

__device__ __forceinline__ void async_cp16(const void* g, void* l) {
  __builtin_amdgcn_global_load_lds(
      (const __attribute__((address_space(1))) uint32_t*)g,
      (__attribute__((address_space(3))) uint32_t*)l, 16, 0, 0);
}

// cast x | features | prototypes -> contiguous bf16 region in ws.
// Also zeroes gemm3's per-tile arrival counters (ws is 0xAA-poisoned per call).
__global__ __launch_bounds__(256) void cast3(
    const float* __restrict__ x, const float* __restrict__ f,
    const float* __restrict__ p, u16* __restrict__ dst,
    int* __restrict__ cnt, int n1, int n2, int n3) {
  if (blockIdx.x == 0) cnt[threadIdx.x] = 0;   // 256 tile counters
  int i = (blockIdx.x * 256 + threadIdx.x) * 4;
  const float* src;
  int local;
  if (i < n1) { src = x; local = i; }
  else if (i < n1 + n2) { src = f; local = i - n1; }
  else if (i < n1 + n2 + n3) { src = p; local = i - n1 - n2; }
  else return;
  f4 v = *(const f4*)(src + local);
  u16x4 o;
  o.x = f2bf(v.x); o.y = f2bf(v.y); o.z = f2bf(v.z); o.w = f2bf(v.w);
  *(u16x4*)(dst + i) = o;
}

// ---- shared main loop: C += A(tile, MxK-rowmajor) @ B(tile, NxK-rowmajor)^T ----
// A,B pre-offset to the tile base row. 16B-chunk XOR swizzle (verified 0 bank conflicts).
template<int TM, int TN>
__device__ __forceinline__ void mainloop(
    const u16* __restrict__ A, const u16* __restrict__ B, int K,
    int kbeg, int kend, int tid, u16* lds, f32x4 (&acc)[TM / 32][TN / 32]) {
  constexpr int BK = 64;
  constexpr int WM = TM / 2, WN = TN / 2;
  constexpr int MT = TM / 32, NT = TN / 32;
  const int lane = tid & 63;
  const int wave = tid >> 6;
  const int wrow = wave >> 1, wcol = wave & 1;

  for (int k0 = kbeg; k0 < kend; k0 += BK) {
    #pragma unroll
    for (int it = 0; it < TM / 32; ++it) {
      int c = it * 256 + tid;            // chunk index = LDS position
      int row = c >> 3, pc = c & 7;
      int gc = pc ^ (row & 7);           // which global 16B chunk lands here
      async_cp16(A + (size_t)row * K + (k0 + gc * 8),
                 &lds[(it * 256 + wave * 64) * 8]);
    }
    #pragma unroll
    for (int it = 0; it < TN / 32; ++it) {
      int c = it * 256 + tid;
      int row = c >> 3, pc = c & 7;
      int gc = pc ^ (row & 7);
      async_cp16(B + (size_t)row * K + (k0 + gc * 8),
                 &lds[TM * BK + (it * 256 + wave * 64) * 8]);
    }
    __syncthreads();

    #pragma unroll
    for (int s = 0; s < 2; ++s) {
      const int h = s * 4 + (lane >> 4);
      bf16x8 afr[MT], bfr[NT];
      #pragma unroll
      for (int i = 0; i < MT; ++i) {
        int r = wrow * WM + i * 16 + (lane & 15);
        afr[i] = *(const bf16x8*)&lds[(r * 8 + (h ^ (r & 7))) * 8];
      }
      #pragma unroll
      for (int j = 0; j < NT; ++j) {
        int r = wcol * WN + j * 16 + (lane & 15);
        bfr[j] = *(const bf16x8*)&lds[TM * BK + (r * 8 + (h ^ (r & 7))) * 8];
      }
      #pragma unroll
      for (int i = 0; i < MT; ++i)
        #pragma unroll
        for (int j = 0; j < NT; ++j)
          acc[i][j] = __builtin_amdgcn_mfma_f32_16x16x32_bf16(afr[i], bfr[j], acc[i][j], 0, 0, 0);
    }
    __syncthreads();
  }
}

// ---- GEMM1+GEMM2 merged: [x; proto](4608 x 1024) @ feat^T, tile 128x64 ----
// x-rows  -> Acat[row, f]=xf*relu(xf), Acat[row, 2048+f]=1-relu(xf)
// p-rows  -> Bcat[row, f]=th*c-al*(1-pres), Bcat[row, 2048+f]=-be*c
// Epilogue: LDS transpose (stride 72 u16, 16B-aligned rows) -> 128B-coalesced
// u16x8 global stores.
// NOTE: no 2nd launch_bounds arg — R6 showed (256,6) caps VGPR->40 and spills
// (FETCH+WRITE +36MB scratch traffic, MfmaUtil 3.5%). Natural alloc = 72-120
// VGPR, 4+ blocks/CU. Never constrain this kernel below 128 VGPR.
__global__ __launch_bounds__(256) void gemm12(
    const u16* __restrict__ xb, const u16* __restrict__ pb,
    const u16* __restrict__ fb, u16* __restrict__ Acat, u16* __restrict__ Bcat,
    const float* __restrict__ alpha, const float* __restrict__ beta,
    const float* __restrict__ theta) {
  constexpr int TM = 128, TN = 64, K = 1024, N = 2048;
  constexpr int MT = TM / 32, NT = TN / 32;    // 4, 2
  constexpr int TSTRIDE = 72;            // u16; 144B rows = 9*16B aligned
  __shared__ u16 lds[(TM + TN) * 64];    // 24576 B; transpose uses 128*72*2=18432 B

  const int tid = threadIdx.x;
  const int lane = tid & 63;
  const int wave = tid >> 6;
  const int wrow = wave >> 1, wcol = wave & 1;
  const int bm_all = blockIdx.x * TM;
  const int bn = blockIdx.y * TN;
  const bool is_x = bm_all < 4096;       // 4096 % 128 == 0: block purely x or proto
  const u16* A = is_x ? xb + (size_t)bm_all * K : pb + (size_t)(bm_all - 4096) * K;
  const u16* B = fb + (size_t)bn * K;

  f32x4 acc[MT][NT] = {};
  mainloop<TM, TN>(A, B, K, 0, K, tid, lds, acc);

  float th = 0.f, al = 0.f, be = 0.f;
  if (!is_x) { th = theta[0]; al = alpha[0]; be = beta[0]; }
  u16* dst = is_x ? Acat : Bcat;
  const int rowbase = is_x ? bm_all : bm_all - 4096;

  #pragma unroll
  for (int half = 0; half < 2; ++half) {
    __syncthreads();   // protect lds reuse (mainloop end / previous half's reads)
    #pragma unroll
    for (int i = 0; i < MT; ++i) {
      #pragma unroll
      for (int j = 0; j < NT; ++j) {
        const int cl = wcol * 32 + j * 16 + (lane & 15);
        #pragma unroll
        for (int r = 0; r < 4; ++r) {
          const int rl = wrow * 64 + i * 16 + (lane >> 4) * 4 + r;
          float v = acc[i][j][r];
          float pres = v > 0.f ? v : 0.f;
          float o;
          if (is_x) o = half == 0 ? v * pres : 1.f - pres;
          else {
            float cc = v * pres;
            o = half == 0 ? th * cc - al * (1.f - pres) : -be * cc;
          }
          lds[rl * TSTRIDE + cl] = f2bf(o);
        }
      }
    }
    __syncthreads();
    #pragma unroll
    for (int v = 0; v < 4; ++v) {
      const int rl = v * 32 + (tid >> 3);
      const int cl = (tid & 7) * 8;
      u16x8 vec = *(const u16x8*)&lds[rl * TSTRIDE + cl];
      *(u16x8*)&dst[(size_t)(rowbase + rl) * (2 * N) + bn + cl + half * N] = vec;
    }
  }
}

// ---- GEMM3 split-K + fused reduce: out = Acat @ Bcat^T over K=4096 ----
// Each z-block stores its partial (thread-linear, coalesced); the LAST arriver
// per tile (device-scope atomic counter) sums the 4 partials and writes out.
// Deterministic (fixed z-order sum). Plain bounds — see gemm12 note.
__global__ __launch_bounds__(256) void gemm3(
    const u16* __restrict__ Acat, const u16* __restrict__ Bcat,
    float* __restrict__ part, int* __restrict__ cnt, float* __restrict__ out) {
  constexpr int TM = 128, TN = 64, K = 4096, N = 512, KSPLIT = 4;
  constexpr int MT = TM / 32, NT = TN / 32;    // 4, 2
  __shared__ u16 lds[(TM + TN) * 64];    // 24576 B

  const int tid = threadIdx.x;
  const int lane = tid & 63;
  const int wave = tid >> 6;
  const int wrow = wave >> 1, wcol = wave & 1;
  const int bm = blockIdx.x * TM;
  const int bn = blockIdx.y * TN;
  const int kbeg = blockIdx.z * (K / KSPLIT);
  const int kend = kbeg + (K / KSPLIT);
  const int tileId = blockIdx.y * 32 + blockIdx.x;   // 0..255

  f32x4 acc[MT][NT] = {};
  mainloop<TM, TN>(Acat + (size_t)bm * K, Bcat + (size_t)bn * K, K, kbeg, kend,
                   tid, lds, acc);

  // store own partial, thread-linear (perfectly coalesced f32x4)
  #pragma unroll
  for (int i = 0; i < MT; ++i)
    #pragma unroll
    for (int j = 0; j < NT; ++j)
      *(f4*)&part[((size_t)blockIdx.z * 256 + tileId) * 8192 +
                  (i * NT + j) * 1024 + tid * 4] = acc[i][j];

  __threadfence();                       // release partial stores device-scope
  __syncthreads();                       // all threads' stores fenced
  volatile int* flag = (volatile int*)lds;
  if (tid == 0) {
    int prev = atomicAdd(&cnt[tileId], 1);   // device-scope by default
    *flag = (prev == KSPLIT - 1) ? 1 : 0;
  }
  __syncthreads();
  if (*flag) {
    __threadfence();                     // acquire: see other blocks' partials
    #pragma unroll
    for (int s = 0; s < 8; ++s) {
      f4 v = {0.f, 0.f, 0.f, 0.f};
      #pragma unroll
      for (int z = 0; z < 4; ++z)
        v += *(const f4*)&part[((size_t)z * 256 + tileId) * 8192 + s * 1024 + tid * 4];
      const int i = s >> 1, j = s & 1;
      const int gr0 = bm + wrow * 64 + i * 16 + (lane >> 4) * 4;
      const int gc = bn + wcol * 32 + j * 16 + (lane & 15);
      out[(size_t)(gr0 + 0) * N + gc] = v.x;
      out[(size_t)(gr0 + 1) * N + gc] = v.y;
      out[(size_t)(gr0 + 2) * N + gc] = v.z;
      out[(size_t)(gr0 + 3) * N + gc] = v.w;
    }
  }
}

extern "C" void kernel_launch(void* const* d_in, const int* in_sizes, int n_in,
                              void* d_out, int out_size, void* d_ws, size_t ws_size,
                              hipStream_t stream) {
  const float* x     = (const float*)d_in[0];
  const float* feat  = (const float*)d_in[1];
  const float* proto = (const float*)d_in[2];
  const float* alpha = (const float*)d_in[3];
  const float* beta  = (const float*)d_in[4];
  const float* theta = (const float*)d_in[5];
  float* out = (float*)d_out;

  constexpr int Bb = 4096, Ii = 1024, Pp = 512, Ff = 2048;

  // ws layout: region0 [0, 33.5MB) serves cast outputs (consumed by gemm12),
  // then is reused for gemm3's fp32 partials (written after gemm12 is done).
  char* ws = (char*)d_ws;
  u16* xb    = (u16*)ws;                              // 8.4 MB
  u16* fb    = xb + (size_t)Bb * Ii;                  // 4.2 MB
  u16* pb    = fb + (size_t)Ff * Ii;                  // 1.0 MB
  float* part = (float*)ws;                           // 33.5 MB (aliases casts)
  size_t r0 = (size_t)4 * 256 * 8192 * 4;             // 33.55 MB
  u16* Acat = (u16*)(ws + r0);                        // 33.6 MB
  u16* Bcat = Acat + (size_t)Bb * 2 * Ff;             // 4.2 MB
  int* cnt  = (int*)(Bcat + (size_t)Pp * 2 * Ff);     // 1 KB (256 counters)

  const int n1 = Bb * Ii, n2 = Ff * Ii, n3 = Pp * Ii;
  cast3<<<((n1 + n2 + n3) / 4 + 255) / 256, 256, 0, stream>>>(
      x, feat, proto, xb, cnt, n1, n2, n3);

  // merged GEMM1+GEMM2: M=4608 (36 row-tiles of 128), N=2048 (32 col-tiles of 64)
  gemm12<<<dim3(36, 32), 256, 0, stream>>>(xb, pb, fb, Acat, Bcat, alpha, beta, theta);

  // GEMM3: 4096x512, K=4096 split 4 ways -> 1024 blocks; last arriver reduces
  gemm3<<<dim3(Bb / 128, Pp / 64, 4), 256, 0, stream>>>(Acat, Bcat, part, cnt, out);
}

// Round 8
// 153.783 us; speedup vs baseline: 1.8986x; 1.8620x over previous
//
#include <hip/hip_runtime.h>
#include <cstdint>

typedef __attribute__((ext_vector_type(8))) short bf16x8;   // 8 bf16 = 4 VGPRs
typedef __attribute__((ext_vector_type(4))) float f32x4;    // MFMA C/D
typedef __attribute__((ext_vector_type(4))) float f4;
typedef __attribute__((ext_vector_type(4))) unsigned short u16x4;
typedef __attribute__((ext_vector_type(8))) unsigned short u16x8;
typedef unsigned short u16;

// JOURNAL (R6/R7): fused last-block reduction with __threadfence() device-scope
// fences inside gemm3 cost ~140 us (L2 writeback/invalidate storms; MfmaUtil 3.5%
// with zero spills). Cross-block reduction stays a separate dispatch.
// JOURNAL (R6): __launch_bounds__(256,6) forced VGPR 72->40 with scratch spills.

__device__ __forceinline__ u16 f2bf(float f) {
  uint32_t u = __builtin_bit_cast(uint32_t, f);
  u += 0x7fffu + ((u >> 16) & 1u);          // round-to-nearest-even
  return (u16)(u >> 16);
}

__device__ __forceinline__ void async_cp16(const void* g, void* l) {
  __builtin_amdgcn_global_load_lds(
      (const __attribute__((address_space(1))) uint32_t*)g,
      (__attribute__((address_space(3))) uint32_t*)l, 16, 0, 0);
}

// cast x | features | prototypes -> contiguous bf16 region in ws
__global__ __launch_bounds__(256) void cast3(
    const float* __restrict__ x, const float* __restrict__ f,
    const float* __restrict__ p, u16* __restrict__ dst,
    int n1, int n2, int n3) {
  int i = (blockIdx.x * 256 + threadIdx.x) * 4;
  const float* src;
  int local;
  if (i < n1) { src = x; local = i; }
  else if (i < n1 + n2) { src = f; local = i - n1; }
  else if (i < n1 + n2 + n3) { src = p; local = i - n1 - n2; }
  else return;
  f4 v = *(const f4*)(src + local);
  u16x4 o;
  o.x = f2bf(v.x); o.y = f2bf(v.y); o.z = f2bf(v.z); o.w = f2bf(v.w);
  *(u16x4*)(dst + i) = o;
}

// ---- shared main loop: C += A(tile, MxK-rowmajor) @ B(tile, NxK-rowmajor)^T ----
// A,B pre-offset to the tile base row. 16B-chunk XOR swizzle (verified 0 bank conflicts).
template<int TM, int TN>
__device__ __forceinline__ void mainloop(
    const u16* __restrict__ A, const u16* __restrict__ B, int K,
    int kbeg, int kend, int tid, u16* lds, f32x4 (&acc)[TM / 32][TN / 32]) {
  constexpr int BK = 64;
  constexpr int WM = TM / 2, WN = TN / 2;
  constexpr int MT = TM / 32, NT = TN / 32;
  const int lane = tid & 63;
  const int wave = tid >> 6;
  const int wrow = wave >> 1, wcol = wave & 1;

  for (int k0 = kbeg; k0 < kend; k0 += BK) {
    #pragma unroll
    for (int it = 0; it < TM / 32; ++it) {
      int c = it * 256 + tid;            // chunk index = LDS position
      int row = c >> 3, pc = c & 7;
      int gc = pc ^ (row & 7);           // which global 16B chunk lands here
      async_cp16(A + (size_t)row * K + (k0 + gc * 8),
                 &lds[(it * 256 + wave * 64) * 8]);
    }
    #pragma unroll
    for (int it = 0; it < TN / 32; ++it) {
      int c = it * 256 + tid;
      int row = c >> 3, pc = c & 7;
      int gc = pc ^ (row & 7);
      async_cp16(B + (size_t)row * K + (k0 + gc * 8),
                 &lds[TM * BK + (it * 256 + wave * 64) * 8]);
    }
    __syncthreads();

    #pragma unroll
    for (int s = 0; s < 2; ++s) {
      const int h = s * 4 + (lane >> 4);
      bf16x8 afr[MT], bfr[NT];
      #pragma unroll
      for (int i = 0; i < MT; ++i) {
        int r = wrow * WM + i * 16 + (lane & 15);
        afr[i] = *(const bf16x8*)&lds[(r * 8 + (h ^ (r & 7))) * 8];
      }
      #pragma unroll
      for (int j = 0; j < NT; ++j) {
        int r = wcol * WN + j * 16 + (lane & 15);
        bfr[j] = *(const bf16x8*)&lds[TM * BK + (r * 8 + (h ^ (r & 7))) * 8];
      }
      #pragma unroll
      for (int i = 0; i < MT; ++i)
        #pragma unroll
        for (int j = 0; j < NT; ++j)
          acc[i][j] = __builtin_amdgcn_mfma_f32_16x16x32_bf16(afr[i], bfr[j], acc[i][j], 0, 0, 0);
    }
    __syncthreads();
  }
}

// ---- GEMM1+GEMM2 merged: [x; proto](4608 x 1024) @ feat^T, tile 128x64 ----
// x-rows  -> Acat[row, f]=xf*relu(xf), Acat[row, 2048+f]=1-relu(xf)
// p-rows  -> Bcat[row, f]=th*c-al*(1-pres), Bcat[row, 2048+f]=-be*c
// Epilogue: LDS transpose (stride 72 u16, 16B-aligned rows) -> 128B-coalesced
// u16x8 global stores. Natural VGPR alloc (~95-120); do NOT cap below 128.
__global__ __launch_bounds__(256) void gemm12(
    const u16* __restrict__ xb, const u16* __restrict__ pb,
    const u16* __restrict__ fb, u16* __restrict__ Acat, u16* __restrict__ Bcat,
    const float* __restrict__ alpha, const float* __restrict__ beta,
    const float* __restrict__ theta) {
  constexpr int TM = 128, TN = 64, K = 1024, N = 2048;
  constexpr int MT = TM / 32, NT = TN / 32;    // 4, 2
  constexpr int TSTRIDE = 72;            // u16; 144B rows = 9*16B aligned
  __shared__ u16 lds[(TM + TN) * 64];    // 24576 B; transpose uses 128*72*2=18432 B

  const int tid = threadIdx.x;
  const int lane = tid & 63;
  const int wave = tid >> 6;
  const int wrow = wave >> 1, wcol = wave & 1;
  const int bm_all = blockIdx.x * TM;
  const int bn = blockIdx.y * TN;
  const bool is_x = bm_all < 4096;       // 4096 % 128 == 0: block purely x or proto
  const u16* A = is_x ? xb + (size_t)bm_all * K : pb + (size_t)(bm_all - 4096) * K;
  const u16* B = fb + (size_t)bn * K;

  f32x4 acc[MT][NT] = {};
  mainloop<TM, TN>(A, B, K, 0, K, tid, lds, acc);

  float th = 0.f, al = 0.f, be = 0.f;
  if (!is_x) { th = theta[0]; al = alpha[0]; be = beta[0]; }
  u16* dst = is_x ? Acat : Bcat;
  const int rowbase = is_x ? bm_all : bm_all - 4096;

  #pragma unroll
  for (int half = 0; half < 2; ++half) {
    __syncthreads();   // protect lds reuse (mainloop end / previous half's reads)
    #pragma unroll
    for (int i = 0; i < MT; ++i) {
      #pragma unroll
      for (int j = 0; j < NT; ++j) {
        const int cl = wcol * 32 + j * 16 + (lane & 15);
        #pragma unroll
        for (int r = 0; r < 4; ++r) {
          const int rl = wrow * 64 + i * 16 + (lane >> 4) * 4 + r;
          float v = acc[i][j][r];
          float pres = v > 0.f ? v : 0.f;
          float o;
          if (is_x) o = half == 0 ? v * pres : 1.f - pres;
          else {
            float cc = v * pres;
            o = half == 0 ? th * cc - al * (1.f - pres) : -be * cc;
          }
          lds[rl * TSTRIDE + cl] = f2bf(o);
        }
      }
    }
    __syncthreads();
    #pragma unroll
    for (int v = 0; v < 4; ++v) {
      const int rl = v * 32 + (tid >> 3);
      const int cl = (tid & 7) * 8;
      u16x8 vec = *(const u16x8*)&lds[rl * TSTRIDE + cl];
      *(u16x8*)&dst[(size_t)(rowbase + rl) * (2 * N) + bn + cl + half * N] = vec;
    }
  }
}

// ---- GEMM3 split-K: part[z] = Acat @ Bcat^T partial, tile 128x64, KSPLIT=4 ----
// Partials stored in thread-linear fragment order; reduce kernel re-maps.
// EXPERIMENT R8: __launch_bounds__(256,8) — m69 says waves/CU steps at VGPR
// {64,128,256}; at 72 we get 16 waves/CU, at <=64 we get 32 (8 blocks/CU).
// If this spills (FETCH/WRITE inflate like R6), revert to plain bounds.
__global__ __launch_bounds__(256, 8) void gemm3(
    const u16* __restrict__ Acat, const u16* __restrict__ Bcat,
    float* __restrict__ part) {
  constexpr int TM = 128, TN = 64, K = 4096, KSPLIT = 4;
  constexpr int MT = TM / 32, NT = TN / 32;    // 4, 2
  __shared__ u16 lds[(TM + TN) * 64];    // 24576 B

  const int tid = threadIdx.x;
  const int bm = blockIdx.x * TM;
  const int bn = blockIdx.y * TN;
  const int kbeg = blockIdx.z * (K / KSPLIT);
  const int kend = kbeg + (K / KSPLIT);

  f32x4 acc[MT][NT] = {};
  mainloop<TM, TN>(Acat + (size_t)bm * K, Bcat + (size_t)bn * K, K, kbeg, kend,
                   tid, lds, acc);

  // tile linear id: z * 256 + by * 32 + bx; per-tile 8192 floats (32 KB)
  const size_t pbase =
      ((size_t)blockIdx.z * 256 + blockIdx.y * 32 + blockIdx.x) * 8192;
  #pragma unroll
  for (int i = 0; i < MT; ++i)
    #pragma unroll
    for (int j = 0; j < NT; ++j)
      *(f4*)&part[pbase + (i * NT + j) * 1024 + tid * 4] = acc[i][j];
}

// ---- reduce partials over z, scatter to out (same thread mapping as gemm3) ----
__global__ __launch_bounds__(256) void reduce4(
    const float* __restrict__ part, float* __restrict__ out) {
  constexpr int N = 512;
  const int tid = threadIdx.x;
  const int lane = tid & 63;
  const int wave = tid >> 6;
  const int wrow = wave >> 1, wcol = wave & 1;
  const int tileId = blockIdx.x;           // 0..255 = by*32+bx
  const int bm = (tileId & 31) * 128;
  const int bn = (tileId >> 5) * 64;

  #pragma unroll
  for (int s = 0; s < 8; ++s) {
    f4 v = {0.f, 0.f, 0.f, 0.f};
    #pragma unroll
    for (int z = 0; z < 4; ++z)
      v += *(const f4*)&part[((size_t)z * 256 + tileId) * 8192 + s * 1024 + tid * 4];
    const int i = s >> 1, j = s & 1;
    const int gr0 = bm + wrow * 64 + i * 16 + (lane >> 4) * 4;
    const int gc = bn + wcol * 32 + j * 16 + (lane & 15);
    out[(size_t)(gr0 + 0) * N + gc] = v.x;
    out[(size_t)(gr0 + 1) * N + gc] = v.y;
    out[(size_t)(gr0 + 2) * N + gc] = v.z;
    out[(size_t)(gr0 + 3) * N + gc] = v.w;
  }
}

extern "C" void kernel_launch(void* const* d_in, const int* in_sizes, int n_in,
                              void* d_out, int out_size, void* d_ws, size_t ws_size,
                              hipStream_t stream) {
  const float* x     = (const float*)d_in[0];
  const float* feat  = (const float*)d_in[1];
  const float* proto = (const float*)d_in[2];
  const float* alpha = (const float*)d_in[3];
  const float* beta  = (const float*)d_in[4];
  const float* theta = (const float*)d_in[5];
  float* out = (float*)d_out;

  constexpr int Bb = 4096, Ii = 1024, Pp = 512, Ff = 2048;

  // ws layout: region0 [0, 33.5MB) serves cast outputs (consumed by gemm12),
  // then is reused for gemm3's fp32 partials (written after gemm12 is done).
  char* ws = (char*)d_ws;
  u16* xb    = (u16*)ws;                              // 8.4 MB
  u16* fb    = xb + (size_t)Bb * Ii;                  // 4.2 MB
  u16* pb    = fb + (size_t)Ff * Ii;                  // 1.0 MB
  float* part = (float*)ws;                           // 33.5 MB (aliases casts)
  size_t r0 = (size_t)4 * 256 * 8192 * 4;             // 33.55 MB
  u16* Acat = (u16*)(ws + r0);                        // 33.6 MB
  u16* Bcat = Acat + (size_t)Bb * 2 * Ff;             // 4.2 MB  (total ~71.3 MB)

  const int n1 = Bb * Ii, n2 = Ff * Ii, n3 = Pp * Ii;
  cast3<<<((n1 + n2 + n3) / 4 + 255) / 256, 256, 0, stream>>>(
      x, feat, proto, xb, n1, n2, n3);

  // merged GEMM1+GEMM2: M=4608 (36 row-tiles of 128), N=2048 (32 col-tiles of 64)
  gemm12<<<dim3(36, 32), 256, 0, stream>>>(xb, pb, fb, Acat, Bcat, alpha, beta, theta);

  // GEMM3: 4096x512, K=4096 split 4 ways -> 1024 blocks, partials to ws
  gemm3<<<dim3(Bb / 128, Pp / 64, 4), 256, 0, stream>>>(Acat, Bcat, part);

  // reduce z=0..3 -> out
  reduce4<<<256, 256, 0, stream>>>(part, out);
}

// Round 9
// 148.414 us; speedup vs baseline: 1.9672x; 1.0362x over previous
//
#include <hip/hip_runtime.h>
#include <cstdint>

typedef __attribute__((ext_vector_type(8))) short bf16x8;    // 8 bf16 = 4 VGPRs
typedef __attribute__((ext_vector_type(16))) float f32x16;   // 32x32 MFMA C/D
typedef __attribute__((ext_vector_type(4))) float f4;
typedef __attribute__((ext_vector_type(8))) unsigned short u16x8;
typedef unsigned short u16;

// JOURNAL:
// R6: __launch_bounds__(256,6) forced VGPR 72->40, scratch spills (+36MB traffic).
// R7: device-scope __threadfence() reduction inside gemm3 = L2 writeback storms,
//     ~140us penalty. Cross-block reduction stays a separate dispatch.
// R8: (256,8) neutral->slightly worse; residency saturated at ~4 blocks/CU.
//     Remaining cost is per-iteration issue + barrier drain -> use 32x32 MFMA.

__device__ __forceinline__ u16 f2bf(float f) {
  uint32_t u = __builtin_bit_cast(uint32_t, f);
  u += 0x7fffu + ((u >> 16) & 1u);          // round-to-nearest-even
  return (u16)(u >> 16);
}

__device__ __forceinline__ void async_cp16(const void* g, void* l) {
  __builtin_amdgcn_global_load_lds(
      (const __attribute__((address_space(1))) uint32_t*)g,
      (__attribute__((address_space(3))) uint32_t*)l, 16, 0, 0);
}

// cast x | features | prototypes -> contiguous bf16 region in ws (8 elem/thread)
__global__ __launch_bounds__(256) void cast3(
    const float* __restrict__ x, const float* __restrict__ f,
    const float* __restrict__ p, u16* __restrict__ dst,
    int n1, int n2, int n3) {
  int i = (blockIdx.x * 256 + threadIdx.x) * 8;
  const float* src;
  int local;
  if (i < n1) { src = x; local = i; }
  else if (i < n1 + n2) { src = f; local = i - n1; }
  else if (i < n1 + n2 + n3) { src = p; local = i - n1 - n2; }
  else return;
  f4 a = *(const f4*)(src + local);
  f4 b = *(const f4*)(src + local + 4);
  u16x8 o;
  o[0] = f2bf(a.x); o[1] = f2bf(a.y); o[2] = f2bf(a.z); o[3] = f2bf(a.w);
  o[4] = f2bf(b.x); o[5] = f2bf(b.y); o[6] = f2bf(b.z); o[7] = f2bf(b.w);
  *(u16x8*)(dst + i) = o;
}

// ---- shared main loop (TM=128, TN=64): C += A @ B^T with 32x32x16 MFMA ----
// A,B pre-offset to tile base row; 16B-chunk XOR swizzle (0 bank conflicts).
// Wave grid 2x2: wave covers 64 rows x 32 cols = 2 stacked 32x32 acc tiles.
// A frag: m = lane&31, k = kstep*16 + (lane>>5)*8 + 0..7 (contiguous b128).
__device__ __forceinline__ void mainloop(
    const u16* __restrict__ A, const u16* __restrict__ B, int K,
    int kbeg, int kend, int tid, u16* lds, f32x16 (&acc)[2]) {
  constexpr int TM = 128, TN = 64, BK = 64;
  const int lane = tid & 63;
  const int wave = tid >> 6;
  const int wrow = wave >> 1, wcol = wave & 1;

  for (int k0 = kbeg; k0 < kend; k0 += BK) {
    #pragma unroll
    for (int it = 0; it < TM / 32; ++it) {
      int c = it * 256 + tid;            // chunk index = LDS position
      int row = c >> 3, pc = c & 7;
      int gc = pc ^ (row & 7);           // which global 16B chunk lands here
      async_cp16(A + (size_t)row * K + (k0 + gc * 8),
                 &lds[(it * 256 + wave * 64) * 8]);
    }
    #pragma unroll
    for (int it = 0; it < TN / 32; ++it) {
      int c = it * 256 + tid;
      int row = c >> 3, pc = c & 7;
      int gc = pc ^ (row & 7);
      async_cp16(B + (size_t)row * K + (k0 + gc * 8),
                 &lds[TM * BK + (it * 256 + wave * 64) * 8]);
    }
    __syncthreads();

    #pragma unroll
    for (int s = 0; s < 4; ++s) {        // 4 k-steps of K=16
      const int h = s * 2 + (lane >> 5); // 16B chunk along K this lane needs
      const int rb = wcol * 32 + (lane & 31);
      bf16x8 bfr = *(const bf16x8*)&lds[TM * BK + (rb * 8 + (h ^ (rb & 7))) * 8];
      #pragma unroll
      for (int i = 0; i < 2; ++i) {
        const int ra = wrow * 64 + i * 32 + (lane & 31);
        bf16x8 afr = *(const bf16x8*)&lds[(ra * 8 + (h ^ (ra & 7))) * 8];
        acc[i] = __builtin_amdgcn_mfma_f32_32x32x16_bf16(afr, bfr, acc[i], 0, 0, 0);
      }
    }
    __syncthreads();
  }
}

// 32x32 C/D mapping (m74/m101 verified): col = lane&31,
// row = (reg&3) + 8*(reg>>2) + 4*(lane>>5), reg in [0,16).

// ---- GEMM1+GEMM2 merged: [x; proto](4608 x 1024) @ feat^T, tile 128x64 ----
// x-rows  -> Acat[row, f]=xf*relu(xf), Acat[row, 2048+f]=1-relu(xf)
// p-rows  -> Bcat[row, f]=th*c-al*(1-pres), Bcat[row, 2048+f]=-be*c
// Epilogue: LDS transpose (stride 72 u16) -> 128B-coalesced u16x8 stores.
__global__ __launch_bounds__(256) void gemm12(
    const u16* __restrict__ xb, const u16* __restrict__ pb,
    const u16* __restrict__ fb, u16* __restrict__ Acat, u16* __restrict__ Bcat,
    const float* __restrict__ alpha, const float* __restrict__ beta,
    const float* __restrict__ theta) {
  constexpr int TM = 128, TN = 64, K = 1024, N = 2048;
  constexpr int TSTRIDE = 72;            // u16; 144B rows = 9*16B aligned
  __shared__ u16 lds[(TM + TN) * 64];    // 24576 B; transpose uses 18432 B

  const int tid = threadIdx.x;
  const int lane = tid & 63;
  const int wave = tid >> 6;
  const int wrow = wave >> 1, wcol = wave & 1;
  const int bm_all = blockIdx.x * TM;
  const int bn = blockIdx.y * TN;
  const bool is_x = bm_all < 4096;       // block purely x or proto (4096%128==0)
  const u16* A = is_x ? xb + (size_t)bm_all * K : pb + (size_t)(bm_all - 4096) * K;
  const u16* B = fb + (size_t)bn * K;

  f32x16 acc[2] = {};
  mainloop(A, B, K, 0, K, tid, lds, acc);

  float th = 0.f, al = 0.f, be = 0.f;
  if (!is_x) { th = theta[0]; al = alpha[0]; be = beta[0]; }
  u16* dst = is_x ? Acat : Bcat;
  const int rowbase = is_x ? bm_all : bm_all - 4096;
  const int cl = wcol * 32 + (lane & 31);
  const int rquad = 4 * (lane >> 5);

  #pragma unroll
  for (int half = 0; half < 2; ++half) {
    __syncthreads();   // protect lds reuse (mainloop end / previous half's reads)
    #pragma unroll
    for (int i = 0; i < 2; ++i) {
      #pragma unroll
      for (int r = 0; r < 16; ++r) {
        const int rl = wrow * 64 + i * 32 + (r & 3) + 8 * (r >> 2) + rquad;
        float v = acc[i][r];
        float pres = v > 0.f ? v : 0.f;
        float o;
        if (is_x) o = half == 0 ? v * pres : 1.f - pres;
        else {
          float cc = v * pres;
          o = half == 0 ? th * cc - al * (1.f - pres) : -be * cc;
        }
        lds[rl * TSTRIDE + cl] = f2bf(o);
      }
    }
    __syncthreads();
    #pragma unroll
    for (int v = 0; v < 4; ++v) {
      const int rl = v * 32 + (tid >> 3);
      const int c8 = (tid & 7) * 8;
      u16x8 vec = *(const u16x8*)&lds[rl * TSTRIDE + c8];
      *(u16x8*)&dst[(size_t)(rowbase + rl) * (2 * N) + bn + c8 + half * N] = vec;
    }
  }
}

// ---- GEMM3 split-K: part[z] = Acat @ Bcat^T partial, tile 128x64, KSPLIT=4 ----
// Partials in thread-linear fragment order; reduce4 mirrors the mapping.
__global__ __launch_bounds__(256) void gemm3(
    const u16* __restrict__ Acat, const u16* __restrict__ Bcat,
    float* __restrict__ part) {
  constexpr int TM = 128, TN = 64, K = 4096, KSPLIT = 4;
  __shared__ u16 lds[(TM + TN) * 64];    // 24576 B

  const int tid = threadIdx.x;
  const int bm = blockIdx.x * TM;
  const int bn = blockIdx.y * TN;
  const int kbeg = blockIdx.z * (K / KSPLIT);
  const int kend = kbeg + (K / KSPLIT);

  f32x16 acc[2] = {};
  mainloop(Acat + (size_t)bm * K, Bcat + (size_t)bn * K, K, kbeg, kend,
           tid, lds, acc);

  // tile linear id: z * 256 + by * 32 + bx; per-tile 8192 floats (32 KB)
  const size_t pbase =
      ((size_t)blockIdx.z * 256 + blockIdx.y * 32 + blockIdx.x) * 8192;
  #pragma unroll
  for (int i = 0; i < 2; ++i)
    #pragma unroll
    for (int q = 0; q < 4; ++q) {
      f4 v = {acc[i][q * 4 + 0], acc[i][q * 4 + 1],
              acc[i][q * 4 + 2], acc[i][q * 4 + 3]};
      *(f4*)&part[pbase + (i * 4 + q) * 1024 + tid * 4] = v;
    }
}

// ---- reduce partials over z, scatter to out (mirrors gemm3's mapping) ----
// frag (i,q), reg r=4q+m: row = bm + wrow*64 + i*32 + m + 8q + 4*(lane>>5),
// col = bn + wcol*32 + (lane&31).
__global__ __launch_bounds__(256) void reduce4(
    const float* __restrict__ part, float* __restrict__ out) {
  constexpr int N = 512;
  const int tid = threadIdx.x;
  const int lane = tid & 63;
  const int wave = tid >> 6;
  const int wrow = wave >> 1, wcol = wave & 1;
  const int tileId = blockIdx.x;           // 0..255 = by*32+bx
  const int bm = (tileId & 31) * 128;
  const int bn = (tileId >> 5) * 64;
  const int gc = bn + wcol * 32 + (lane & 31);
  const int rquad = 4 * (lane >> 5);

  #pragma unroll
  for (int s = 0; s < 8; ++s) {            // s = i*4 + q
    f4 v = {0.f, 0.f, 0.f, 0.f};
    #pragma unroll
    for (int z = 0; z < 4; ++z)
      v += *(const f4*)&part[((size_t)z * 256 + tileId) * 8192 + s * 1024 + tid * 4];
    const int i = s >> 2, q = s & 3;
    const int gr0 = bm + wrow * 64 + i * 32 + 8 * q + rquad;
    out[(size_t)(gr0 + 0) * N + gc] = v.x;
    out[(size_t)(gr0 + 1) * N + gc] = v.y;
    out[(size_t)(gr0 + 2) * N + gc] = v.z;
    out[(size_t)(gr0 + 3) * N + gc] = v.w;
  }
}

extern "C" void kernel_launch(void* const* d_in, const int* in_sizes, int n_in,
                              void* d_out, int out_size, void* d_ws, size_t ws_size,
                              hipStream_t stream) {
  const float* x     = (const float*)d_in[0];
  const float* feat  = (const float*)d_in[1];
  const float* proto = (const float*)d_in[2];
  const float* alpha = (const float*)d_in[3];
  const float* beta  = (const float*)d_in[4];
  const float* theta = (const float*)d_in[5];
  float* out = (float*)d_out;

  constexpr int Bb = 4096, Ii = 1024, Pp = 512, Ff = 2048;

  // ws layout: region0 [0, 33.5MB) serves cast outputs (consumed by gemm12),
  // then is reused for gemm3's fp32 partials (written after gemm12 is done).
  char* ws = (char*)d_ws;
  u16* xb    = (u16*)ws;                              // 8.4 MB
  u16* fb    = xb + (size_t)Bb * Ii;                  // 4.2 MB
  u16* pb    = fb + (size_t)Ff * Ii;                  // 1.0 MB
  float* part = (float*)ws;                           // 33.5 MB (aliases casts)
  size_t r0 = (size_t)4 * 256 * 8192 * 4;             // 33.55 MB
  u16* Acat = (u16*)(ws + r0);                        // 33.6 MB
  u16* Bcat = Acat + (size_t)Bb * 2 * Ff;             // 4.2 MB  (total ~71.3 MB)

  const int n1 = Bb * Ii, n2 = Ff * Ii, n3 = Pp * Ii;
  cast3<<<((n1 + n2 + n3) / 8 + 255) / 256, 256, 0, stream>>>(
      x, feat, proto, xb, n1, n2, n3);

  // merged GEMM1+GEMM2: M=4608 (36 row-tiles of 128), N=2048 (32 col-tiles of 64)
  gemm12<<<dim3(36, 32), 256, 0, stream>>>(xb, pb, fb, Acat, Bcat, alpha, beta, theta);

  // GEMM3: 4096x512, K=4096 split 4 ways -> 1024 blocks, partials to ws
  gemm3<<<dim3(Bb / 128, Pp / 64, 4), 256, 0, stream>>>(Acat, Bcat, part);

  // reduce z=0..3 -> out
  reduce4<<<256, 256, 0, stream>>>(part, out);
}